// Round 12
// baseline (337.634 us; speedup 1.0000x reference)
//
#include <hip/hip_runtime.h>
#include <hip/hip_bf16.h>

// ---------------------------------------------------------------------------
// Generator_58737972740271.  R12 (from R11): 32-row tiles for the fused MFMA
// kernels (1024 blocks -> 4 blocks/CU = 16 waves/CU, was 8); Tp becomes 32
// bf16 partials; u/xt LDS layouts padded to stride-40 to break the 16-way
// bank conflict in the T-partial ds_read pattern.  bnlin/prep/dec2 unchanged.
// ---------------------------------------------------------------------------

typedef __hip_bfloat16 bf16;
typedef unsigned short ushort_t;
typedef float v4f __attribute__((ext_vector_type(4)));
typedef short v8s __attribute__((ext_vector_type(8)));
#define MFMA_BF16 __builtin_amdgcn_mfma_f32_16x16x32_bf16

#define NB 32
#define NN 1024

__device__ __forceinline__ float ldin(const void* p, size_t i, int f32){
    return f32 ? ((const float*)p)[i] : __bfloat162float(((const bf16*)p)[i]);
}
__device__ __forceinline__ float bf2f(ushort_t u){
    return __uint_as_float((unsigned)u << 16);
}
__device__ __forceinline__ ushort_t f2bf(float v){
    bf16 h = __float2bfloat16(v);
    ushort_t s; __builtin_memcpy(&s, &h, 2);
    return s;
}
__device__ __forceinline__ void unpack8(uint4 v, float* f){
    f[0] = __uint_as_float(v.x << 16);
    f[1] = __uint_as_float(v.x & 0xffff0000u);
    f[2] = __uint_as_float(v.y << 16);
    f[3] = __uint_as_float(v.y & 0xffff0000u);
    f[4] = __uint_as_float(v.z << 16);
    f[5] = __uint_as_float(v.z & 0xffff0000u);
    f[6] = __uint_as_float(v.w << 16);
    f[7] = __uint_as_float(v.w & 0xffff0000u);
}

__device__ __forceinline__ int detect_dev(const void* inp){
    __shared__ int sflag;
    int t = threadIdx.x;
    if (t < 64){
        unsigned v = ((const unsigned*)inp)[t];
        unsigned long long m = __ballot((v & 0x80008000u) != 0u);
        if (t == 0) sflag = (__popcll(m) > 4) ? 1 : 0;
    }
    __syncthreads();
    return sflag;
}

// ---------------- prep: weights --------------------------------------------
struct PrepArgs {
    const void* w[11];
    int K[11], O[11], off[11];
};

__global__ __launch_bounds__(256) void k_prep(PrepArgs a, float* __restrict__ wpf,
                                              ushort_t* __restrict__ whi, ushort_t* __restrict__ wlo,
                                              const void* __restrict__ detin){
    int f32 = detect_dev(detin);
    int s = blockIdx.y;
    int idx = blockIdx.x*256 + threadIdx.x;
    if (s < 6){
        int K = a.K[s], O = a.O[s];
        if (idx >= K*O) return;
        int k = idx / O, j = idx - k*O;
        wpf[a.off[s] + idx] = ldin(a.w[s], (size_t)j*K + k, f32);
    } else {
        if (idx >= 16384) return;
        int n = idx >> 7, k = idx & 127;
        float v = ldin(a.w[s], (size_t)n*128 + k, f32);
        ushort_t h = f2bf(v);
        ushort_t l = f2bf(v - bf2f(h));
        int di = (s - 6)*16384 + ((k >> 3)*128 + n)*8 + (k & 7);
        whi[di] = h; wlo[di] = l;
    }
}

// ---------------- fused linear + BatchNorm(channel=n) + ReLU (VALU) --------
template<int K, int O, bool EXTIN>
__global__ __launch_bounds__(128) void k_bnlin(
    const void* __restrict__ xin, const float* __restrict__ Wt,
    const void* __restrict__ bias, const void* __restrict__ bng,
    const void* __restrict__ bnb, ushort_t* __restrict__ out,
    const void* __restrict__ detin)
{
    int f32 = detect_dev(detin);
    constexpr int BR  = O/16;
    constexpr int NBT = 32/BR;
    constexpr int G   = K/8;
    __shared__ __align__(16) float wt[K*O];
    __shared__ __align__(16) float xst[2][K*36];
    int t = threadIdx.x;
    int w = t >> 6, lane = t & 63;
    int n = blockIdx.x*2 + w;

    for (int i = t; i < K*O/4; i += 128)
        ((float4*)wt)[i] = ((const float4*)Wt)[i];
    for (int i = lane; i < 32*G; i += 64){
        int b = i / G, g = i - b*G;
        float f[8];
        if (EXTIN && f32){
            const float* src = (const float*)xin + ((size_t)b*NN + n)*K + g*8;
            float4 v0 = ((const float4*)src)[0];
            float4 v1 = ((const float4*)src)[1];
            f[0]=v0.x; f[1]=v0.y; f[2]=v0.z; f[3]=v0.w;
            f[4]=v1.x; f[5]=v1.y; f[6]=v1.z; f[7]=v1.w;
        } else {
            uint4 v = *(const uint4*)((const ushort_t*)xin + ((size_t)b*NN + n)*K + (size_t)g*8);
            unpack8(v, f);
        }
        #pragma unroll
        for (int j=0;j<8;j++) xst[w][(g*8+j)*36 + b] = f[j];
    }
    __syncthreads();

    int bt = lane % NBT, jt = lane / NBT;
    int b0 = bt*BR, j0 = jt*8;
    const float* xw = xst[w];
    float acc[BR][8];
    #pragma unroll
    for (int i=0;i<BR;i++)
        #pragma unroll
        for (int j=0;j<8;j++) acc[i][j] = 0.f;

    for (int k = 0; k < K; k++){
        float xv[BR], wv[8];
        #pragma unroll
        for (int i=0;i<BR;i+=4)
            *(float4*)&xv[i] = *(const float4*)&xw[k*36 + b0 + i];
        *(float4*)&wv[0] = *(const float4*)&wt[k*O + j0];
        *(float4*)&wv[4] = *(const float4*)&wt[k*O + j0 + 4];
        #pragma unroll
        for (int i=0;i<BR;i++)
            #pragma unroll
            for (int j=0;j<8;j++) acc[i][j] = fmaf(xv[i], wv[j], acc[i][j]);
    }

    float bj[8];
    #pragma unroll
    for (int j=0;j<8;j++) bj[j] = ldin(bias, j0+j, f32);
    float s1 = 0.f, s2 = 0.f;
    #pragma unroll
    for (int i=0;i<BR;i++)
        #pragma unroll
        for (int j=0;j<8;j++){
            float a = acc[i][j] + bj[j];
            acc[i][j] = a; s1 += a; s2 = fmaf(a, a, s2);
        }
    #pragma unroll
    for (int off = 32; off > 0; off >>= 1){
        s1 += __shfl_down(s1, off);
        s2 += __shfl_down(s2, off);
    }
    s1 = __shfl(s1, 0); s2 = __shfl(s2, 0);
    const float M = 32.f * O;
    float m  = s1 / M;
    float vv = s2 / M - m*m;
    float rs = rsqrtf(vv + 1e-5f);
    float gv = ldin(bng, n, f32), bv = ldin(bnb, n, f32);
    #pragma unroll
    for (int i=0;i<BR;i++){
        union { uint4 u; ushort_t s[8]; } pk;
        #pragma unroll
        for (int j=0;j<8;j++)
            pk.s[j] = f2bf(fmaxf(fmaf(gv*(acc[i][j]-m), rs, bv), 0.f));
        *(uint4*)(out + ((size_t)(b0+i)*NN + n)*O + j0) = pk.u;
    }
}

// ---------------- shared tails, 32-row tiles -------------------------------
// Block owns rows [row0, row0+32).  Lane owns values at (r = m*16+quad*4+reg,
// n = w*32+nt*16+col), m<2.  xs: A-layout [k>>3][32r][8] (4096) reused as u
// [n][40r-pad] (5120).  xt: x' [c][40r-pad] (5120).

__device__ __forceinline__ void tail_stage_x32(ushort_t* xs, ushort_t* xt,
                                               const float o[2][8],
                                               int w, int col, int quad){
    #pragma unroll
    for (int nt=0;nt<2;nt++){
        int n = w*32 + nt*16 + col;
        #pragma unroll
        for (int m=0;m<2;m++){
            union { uint2 u2; ushort_t s[4]; } pk;
            #pragma unroll
            for (int reg=0;reg<4;reg++){
                int r = m*16 + quad*4 + reg;
                ushort_t hv = f2bf(o[nt][m*4+reg]);
                xs[((n>>3)*32 + r)*8 + (n&7)] = hv;
                pk.s[reg] = hv;
            }
            *(uint2*)&xt[n*40 + m*16 + quad*4] = pk.u2;
        }
    }
}

__device__ __forceinline__ void tail_write_A32(const ushort_t* xs, ushort_t* A,
                                               size_t row0, int t){
    uint4* dst = (uint4*)(A + row0*128);
    #pragma unroll
    for (int c = 0; c < 2; c++){
        int i = t + c*256;
        int r = i >> 4, kg = i & 15;
        dst[i] = *(const uint4*)&xs[(kg*32 + r)*8];
    }
}

// next linear: U = relu(x'·W^T + b) -> UT; dvec; 32-row T-partial
// Tp[s][b][c][n] (bf16) = sum_r u[r][n] * x'[r][c]  via MFMA (k=32).
__device__ __forceinline__ void tail_lin_relu_T32(ushort_t* xs, ushort_t* xt,
    ushort_t* UT, const ushort_t* Whi, const ushort_t* Wlo, const void* bias,
    float* dvec, ushort_t* Tp,
    size_t row0, int b, int rbase, int t, int w, int col, int quad, int f32)
{
    if (t < 32){
        float s = 0.f;
        #pragma unroll 8
        for (int k=0;k<128;k++){
            float v = bf2f(xs[((k>>3)*32 + t)*8 + (k&7)]);
            s = fmaf(v, v, s);
        }
        dvec[row0 + t] = s;
    }
    v4f acc[2][2];
    #pragma unroll
    for (int m=0;m<2;m++)
        #pragma unroll
        for (int nt=0;nt<2;nt++) acc[m][nt] = (v4f){0.f,0.f,0.f,0.f};
    #pragma unroll
    for (int kt = 0; kt < 4; kt++){
        int kg = kt*4 + quad;
        v8s a[2], bh[2], bl[2];
        #pragma unroll
        for (int nt=0;nt<2;nt++){
            int n = w*32 + nt*16 + col;
            bh[nt] = *(const v8s*)&Whi[(kg*128 + n)*8];
            bl[nt] = *(const v8s*)&Wlo[(kg*128 + n)*8];
        }
        #pragma unroll
        for (int m=0;m<2;m++)
            a[m] = *(const v8s*)&xs[(kg*32 + m*16 + col)*8];
        #pragma unroll
        for (int m=0;m<2;m++)
            #pragma unroll
            for (int nt=0;nt<2;nt++){
                acc[m][nt] = MFMA_BF16(a[m], bh[nt], acc[m][nt], 0, 0, 0);
                acc[m][nt] = MFMA_BF16(a[m], bl[nt], acc[m][nt], 0, 0, 0);
            }
    }
    float u[2][8];
    #pragma unroll
    for (int nt=0;nt<2;nt++){
        int n = w*32 + nt*16 + col;
        float bn = ldin(bias, n, f32);
        #pragma unroll
        for (int m=0;m<2;m++)
            #pragma unroll
            for (int reg=0;reg<4;reg++)
                u[nt][m*4+reg] = fmaxf(acc[m][nt][reg] + bn, 0.f);
    }
    __syncthreads();           // xs reads (a-frags, dvec) done
    #pragma unroll
    for (int nt=0;nt<2;nt++){
        int n = w*32 + nt*16 + col;
        #pragma unroll
        for (int m=0;m<2;m++){
            union { uint2 u2; ushort_t s[4]; } pk;
            #pragma unroll
            for (int reg=0;reg<4;reg++)
                pk.s[reg] = f2bf(u[nt][m*4+reg]);
            *(uint2*)&xs[n*40 + m*16 + quad*4] = pk.u2;   // u in [n][40r]
        }
    }
    __syncthreads();
    #pragma unroll
    for (int c = 0; c < 2; c++){
        int i = t + c*256;
        int n = i >> 2, sg = i & 3;
        *(uint4*)&UT[((size_t)b*128 + n)*1024 + rbase + sg*8] =
            *(const uint4*)&xs[n*40 + sg*8];
    }
    // ---- T-partial over own 32 rows: A = u [n][40r], B = x' [c][40r] ----
    v4f tacc[4][4];
    #pragma unroll
    for (int m=0;m<4;m++)
        #pragma unroll
        for (int q=0;q<4;q++) tacc[m][q] = (v4f){0.f,0.f,0.f,0.f};
    int wn = (w & 1)*64, wc = (w >> 1)*64;
    {
        int kg = quad;
        v8s a[4], bb[4];
        #pragma unroll
        for (int m=0;m<4;m++)
            a[m] = *(const v8s*)&xs[(wn + m*16 + col)*40 + kg*8];
        #pragma unroll
        for (int q=0;q<4;q++)
            bb[q] = *(const v8s*)&xt[(wc + q*16 + col)*40 + kg*8];
        #pragma unroll
        for (int m=0;m<4;m++)
            #pragma unroll
            for (int q=0;q<4;q++)
                tacc[m][q] = MFMA_BF16(a[m], bb[q], tacc[m][q], 0, 0, 0);
    }
    int s32 = (int)((row0 >> 5) & 31);
    ushort_t* dst = Tp + ((size_t)(s32*NB + b) << 14);   // [c][n] bf16
    #pragma unroll
    for (int m=0;m<4;m++)
        #pragma unroll
        for (int q=0;q<4;q++){
            int c = wc + q*16 + col;
            union { uint2 u2; ushort_t s[4]; } pk;
            #pragma unroll
            for (int reg=0;reg<4;reg++)
                pk.s[reg] = f2bf(tacc[m][q][reg]);       // n-consecutive
            *(uint2*)&dst[c*128 + wn + m*16 + quad*4] = pk.u2;
        }
}

// ---------------- fused: enc3 sigmoid + relation-1 U + T-partial -----------
__global__ __launch_bounds__(256) void k_linfuse0(
    const ushort_t* __restrict__ xin,                 // E2, row-major
    const ushort_t* __restrict__ W3h, const ushort_t* __restrict__ W3l,
    const void* __restrict__ b3,
    const ushort_t* __restrict__ W1h, const ushort_t* __restrict__ W1l,
    const void* __restrict__ b1,
    ushort_t* __restrict__ A, ushort_t* __restrict__ UT,
    float* __restrict__ dvec, ushort_t* __restrict__ Tp,
    const void* __restrict__ detin)
{
    __shared__ __align__(16) ushort_t xs[5120];
    __shared__ __align__(16) ushort_t xt[5120];
    int f32 = detect_dev(detin);
    int t = threadIdx.x;
    size_t row0 = (size_t)blockIdx.x * 32;
    int b = (int)(row0 >> 10), rbase = (int)(row0 & 1023);
    {
        const uint4* src = (const uint4*)(xin + row0*128);
        #pragma unroll
        for (int c = 0; c < 2; c++){
            int i = t + c*256;
            int r = i >> 4, kg = i & 15;
            *(uint4*)&xs[(kg*32 + r)*8] = src[i];
        }
    }
    __syncthreads();
    int w = t >> 6, lane = t & 63;
    int col = lane & 15, quad = lane >> 4;
    v4f acc[2][2];
    #pragma unroll
    for (int m=0;m<2;m++)
        #pragma unroll
        for (int nt=0;nt<2;nt++) acc[m][nt] = (v4f){0.f,0.f,0.f,0.f};
    #pragma unroll
    for (int kt = 0; kt < 4; kt++){
        int kg = kt*4 + quad;
        v8s a[2], bh[2], bl[2];
        #pragma unroll
        for (int nt=0;nt<2;nt++){
            int n = w*32 + nt*16 + col;
            bh[nt] = *(const v8s*)&W3h[(kg*128 + n)*8];
            bl[nt] = *(const v8s*)&W3l[(kg*128 + n)*8];
        }
        #pragma unroll
        for (int m=0;m<2;m++)
            a[m] = *(const v8s*)&xs[(kg*32 + m*16 + col)*8];
        #pragma unroll
        for (int m=0;m<2;m++)
            #pragma unroll
            for (int nt=0;nt<2;nt++){
                acc[m][nt] = MFMA_BF16(a[m], bh[nt], acc[m][nt], 0, 0, 0);
                acc[m][nt] = MFMA_BF16(a[m], bl[nt], acc[m][nt], 0, 0, 0);
            }
    }
    float o[2][8];
    #pragma unroll
    for (int nt=0;nt<2;nt++){
        int n = w*32 + nt*16 + col;
        float bn = ldin(b3, n, f32);
        #pragma unroll
        for (int m=0;m<2;m++)
            #pragma unroll
            for (int reg=0;reg<4;reg++){
                float v = acc[m][nt][reg] + bn;
                o[nt][m*4+reg] = 1.f/(1.f+expf(-v));
            }
    }
    __syncthreads();
    tail_stage_x32(xs, xt, o, w, col, quad);
    __syncthreads();
    tail_write_A32(xs, A, row0, t);
    tail_lin_relu_T32(xs, xt, UT, W1h, W1l, b1, dvec, Tp,
                      row0, b, rbase, t, w, col, quad, f32);
}

// ---------------- reduce 32 bf16 partials -> Tt hi/lo (MFMA-B layout) ------
__global__ __launch_bounds__(256) void k_tredb(const ushort_t* __restrict__ Tp,
                                               ushort_t* __restrict__ Thi, ushort_t* __restrict__ Tlo){
    int tau = blockIdx.x*256 + threadIdx.x;     // 65536 total
    int b = tau >> 11;
    int j2 = tau & 2047;
    int cg = j2 >> 7, n = j2 & 127;
    float sum[8] = {0,0,0,0,0,0,0,0};
    #pragma unroll
    for (int s = 0; s < 32; s++){
        const ushort_t* src = Tp + ((size_t)(s*NB + b) << 14) + cg*8*128 + n;
        #pragma unroll
        for (int cc = 0; cc < 8; cc++)
            sum[cc] += bf2f(src[cc*128]);
    }
    union { uint4 u; ushort_t s[8]; } ph, pl;
    #pragma unroll
    for (int cc = 0; cc < 8; cc++){
        ushort_t h = f2bf(sum[cc]);
        ph.s[cc] = h;
        pl.s[cc] = f2bf(sum[cc] - bf2f(h));
    }
    size_t di = ((size_t)b << 14) + ((size_t)cg*128 + n)*8;
    *(uint4*)&Thi[di] = ph.u;
    *(uint4*)&Tlo[di] = pl.u;
}

// ---------------- fused: relout_r (+ lin_{r+1} + T-partial unless LAST) ----
template<int LAST>
__global__ __launch_bounds__(256) void k_relfuse(
    ushort_t* __restrict__ x, ushort_t* __restrict__ UT,
    const ushort_t* __restrict__ Thi, const ushort_t* __restrict__ Tlo,
    float* __restrict__ dvec,
    const void* __restrict__ psi, const void* __restrict__ phi, const void* __restrict__ wr,
    const ushort_t* __restrict__ Wnh, const ushort_t* __restrict__ Wnl,
    const void* __restrict__ bnext, ushort_t* __restrict__ Tp,
    const void* __restrict__ detin)
{
    __shared__ __align__(16) ushort_t xs[5120];
    __shared__ __align__(16) ushort_t xt[5120];
    int f32 = detect_dev(detin);
    int t = threadIdx.x;
    size_t row0 = (size_t)blockIdx.x * 32;
    int b = (int)(row0 >> 10), rbase = (int)(row0 & 1023);
    {
        const uint4* src = (const uint4*)(x + row0*128);
        #pragma unroll
        for (int c = 0; c < 2; c++){
            int i = t + c*256;
            int r = i >> 4, kg = i & 15;
            *(uint4*)&xs[(kg*32 + r)*8] = src[i];
        }
    }
    __syncthreads();
    float alpha = ldin(wr,0,f32) * ldin(psi,0,f32) * ldin(phi,0,f32) * (1.f/1024.f);
    int w = t >> 6, lane = t & 63;
    int col = lane & 15, quad = lane >> 4;
    const ushort_t* sh = Thi + ((size_t)b << 14);
    const ushort_t* sl = Tlo + ((size_t)b << 14);
    v4f acc[2][2];
    #pragma unroll
    for (int m=0;m<2;m++)
        #pragma unroll
        for (int nt=0;nt<2;nt++) acc[m][nt] = (v4f){0.f,0.f,0.f,0.f};
    #pragma unroll
    for (int kt = 0; kt < 4; kt++){
        int kg = kt*4 + quad;
        v8s a[2], bh[2], bl[2];
        #pragma unroll
        for (int nt=0;nt<2;nt++){
            int n = w*32 + nt*16 + col;
            bh[nt] = *(const v8s*)&sh[(kg*128 + n)*8];
            bl[nt] = *(const v8s*)&sl[(kg*128 + n)*8];
        }
        #pragma unroll
        for (int m=0;m<2;m++)
            a[m] = *(const v8s*)&xs[(kg*32 + m*16 + col)*8];
        #pragma unroll
        for (int m=0;m<2;m++)
            #pragma unroll
            for (int nt=0;nt<2;nt++){
                acc[m][nt] = MFMA_BF16(a[m], bh[nt], acc[m][nt], 0, 0, 0);
                acc[m][nt] = MFMA_BF16(a[m], bl[nt], acc[m][nt], 0, 0, 0);
            }
    }
    float o[2][8];
    #pragma unroll
    for (int m=0;m<2;m++){
        float4 d4 = *(const float4*)&dvec[row0 + m*16 + quad*4];
        const float* dr = (const float*)&d4;
        #pragma unroll
        for (int nt=0;nt<2;nt++){
            int n = w*32 + nt*16 + col;
            uint2 uu = *(const uint2*)&UT[((size_t)b*128 + n)*1024 + rbase + m*16 + quad*4];
            float uf[4];
            uf[0] = __uint_as_float(uu.x << 16);
            uf[1] = __uint_as_float(uu.x & 0xffff0000u);
            uf[2] = __uint_as_float(uu.y << 16);
            uf[3] = __uint_as_float(uu.y & 0xffff0000u);
            #pragma unroll
            for (int reg=0;reg<4;reg++){
                int r = m*16 + quad*4 + reg;
                float xv = bf2f(xs[((n>>3)*32 + r)*8 + (n&7)]);
                o[nt][m*4+reg] = fmaf(alpha, acc[m][nt][reg] - dr[reg]*uf[reg], xv);
            }
        }
    }
    __syncthreads();           // all xs / dvec / UT reads done
    tail_stage_x32(xs, xt, o, w, col, quad);
    __syncthreads();
    tail_write_A32(xs, x, row0, t);
    if (!LAST)
        tail_lin_relu_T32(xs, xt, UT, Wnh, Wnl, bnext, dvec, Tp,
                          row0, b, rbase, t, w, col, quad, f32);
}

// ---------------- decoder tail (512 blocks x 8-tile loop) ------------------
__global__ __launch_bounds__(256) void k_dec2(
    const ushort_t* __restrict__ x,       // [B,N,64]
    const float* __restrict__ W2t, const void* __restrict__ b2,
    const float* __restrict__ Wct, const void* __restrict__ bcb,
    const float* __restrict__ Wgt, const void* __restrict__ bgb,
    void* __restrict__ out, const void* __restrict__ detin)
{
    int f32 = detect_dev(detin);
    __shared__ __align__(16) float w2[64*32];
    __shared__ __align__(16) float wc[32*28];
    __shared__ __align__(16) float wg[32*4];
    __shared__ __align__(16) float xsd[8][64];
    __shared__ float hs[8][33];
    int t = threadIdx.x;
    for (int i=t;i<512;i+=256)  ((float4*)w2)[i] = ((const float4*)W2t)[i];
    if (t < 224) ((float4*)wc)[t] = ((const float4*)Wct)[t];
    if (t < 32)  ((float4*)wg)[t] = ((const float4*)Wgt)[t];
    int j = t & 31, r = t >> 5;
    for (int tile = blockIdx.x; tile < 4096; tile += 512){
        size_t row0 = (size_t)tile * 8;
        __syncthreads();
        if (t < 64){
            int row = t >> 3, seg = t & 7;
            uint4 v = *(const uint4*)&x[(row0 + row)*64 + seg*8];
            float f[8]; unpack8(v, f);
            *(float4*)&xsd[row][seg*8]   = make_float4(f[0],f[1],f[2],f[3]);
            *(float4*)&xsd[row][seg*8+4] = make_float4(f[4],f[5],f[6],f[7]);
        }
        __syncthreads();
        float a = ldin(b2, j, f32);
        #pragma unroll 8
        for (int k=0;k<64;k++) a = fmaf(xsd[r][k], w2[k*32 + j], a);
        hs[r][j] = fmaxf(a, 0.f);
        __syncthreads();
        float o;
        if (j < 28){
            o = ldin(bcb, j, f32);
            #pragma unroll
            for (int k=0;k<32;k++) o = fmaf(hs[r][k], wc[k*28 + j], o);
        } else {
            int jj = j - 28;
            o = ldin(bgb, jj, f32);
            #pragma unroll
            for (int k=0;k<32;k++) o = fmaf(hs[r][k], wg[k*4 + jj], o);
        }
        size_t oi = (row0 + r)*32 + j;
        if (f32) ((float*)out)[oi] = o;
        else     ((ushort_t*)out)[oi] = f2bf(o);
    }
}

// ---------------------------------------------------------------------------
enum { O_E1=0, O_E2=2048, O_D1=10240, O_D2=18432, O_BC=20480, O_BG=21376 };

extern "C" void kernel_launch(void* const* d_in, const int* in_sizes, int n_in,
                              void* d_out, int out_size, void* d_ws, size_t ws_size,
                              hipStream_t stream)
{
    (void)in_sizes; (void)n_in; (void)out_size; (void)ws_size;
    const void* input = d_in[0];
    const void* e1_W = d_in[1];  const void* e1_b = d_in[2];
    const void* bn1_g = d_in[3]; const void* bn1_b = d_in[4];
    const void* e2_W = d_in[5];  const void* e2_b = d_in[6];
    const void* bn2_g = d_in[7]; const void* bn2_b = d_in[8];
    const void* e3_W = d_in[9];  const void* e3_b = d_in[10];
    const void *rW[4], *rb[4], *rpsi[4], *rphi[4], *rwr[4];
    for (int r = 0; r < 4; r++){
        rW[r]   = d_in[11 + r*5 + 0];
        rb[r]   = d_in[11 + r*5 + 1];
        rpsi[r] = d_in[11 + r*5 + 2];
        rphi[r] = d_in[11 + r*5 + 3];
        rwr[r]  = d_in[11 + r*5 + 4];
    }
    const void* d1_W = d_in[31]; const void* d1_b = d_in[32];
    const void* dbn_g = d_in[33];const void* dbn_b = d_in[34];
    const void* d2_W = d_in[35]; const void* d2_b = d_in[36];
    const void* bc_W = d_in[37]; const void* bc_b = d_in[38];
    const void* bg_W = d_in[39]; const void* bg_b = d_in[40];

    // ---- workspace layout (61.4 MB), float offsets (all 16B-aligned) ----
    float*    ws_f = (float*)d_ws;
    float*    wpf  = ws_f;                          // 21504 f
    float*    dd   = ws_f + 21504;                  // 32768 f
    ushort_t* whi  = (ushort_t*)(ws_f + 54272);     // 5*16384 us
    ushort_t* wlo  = (ushort_t*)(ws_f + 95232);     // 5*16384 us
    ushort_t* Thi  = (ushort_t*)(ws_f + 136192);    // 524288 us
    ushort_t* Tlo  = (ushort_t*)(ws_f + 398336);    // 524288 us
    ushort_t* Tp   = (ushort_t*)(ws_f + 660480);    // 32*32*16384 us (bf16)
    ushort_t* A    = (ushort_t*)(ws_f + 9049088);   // [32768][128] bf16
    ushort_t* UT   = (ushort_t*)(ws_f + 11146240);  // [32][128][1024] bf16
    ushort_t* E2   = (ushort_t*)(ws_f + 13243392);  // [32768][128] bf16
    ushort_t* Cenc = A;                             // [32768][64] overlays A
    ushort_t* Cdec = UT;                            // [32768][64] overlays UT

    PrepArgs pa;
    const void* srcs[11] = {e1_W, e2_W, d1_W, d2_W, bc_W, bg_W,
                            e3_W, rW[0], rW[1], rW[2], rW[3]};
    const int  Ks[11]   = {32,64,128,64,32,32, 128,128,128,128,128};
    const int  Os[11]   = {64,128,64,32,28,4,  128,128,128,128,128};
    const int  offs[11] = {O_E1,O_E2,O_D1,O_D2,O_BC,O_BG, 0,0,0,0,0};
    for (int i=0;i<11;i++){ pa.w[i]=srcs[i]; pa.K[i]=Ks[i]; pa.O[i]=Os[i]; pa.off[i]=offs[i]; }

    k_prep<<<dim3(64,11), 256, 0, stream>>>(pa, wpf, whi, wlo, input);
    k_bnlin<32,64,true><<<512, 128, 0, stream>>>(input, wpf+O_E1, e1_b, bn1_g, bn1_b, Cenc, input);
    k_bnlin<64,128,false><<<512, 128, 0, stream>>>(Cenc, wpf+O_E2, e2_b, bn2_g, bn2_b, E2, input);
    k_linfuse0<<<1024, 256, 0, stream>>>(E2, whi, wlo, e3_b,
                                         whi + 16384, wlo + 16384, rb[0],
                                         A, UT, dd, Tp, input);

    for (int r = 0; r < 4; r++){
        k_tredb<<<256, 256, 0, stream>>>(Tp, Thi, Tlo);
        if (r < 3)
            k_relfuse<0><<<1024, 256, 0, stream>>>(A, UT, Thi, Tlo, dd,
                rpsi[r], rphi[r], rwr[r],
                whi + (size_t)(2+r)*16384, wlo + (size_t)(2+r)*16384, rb[r+1], Tp, input);
        else
            k_relfuse<1><<<1024, 256, 0, stream>>>(A, UT, Thi, Tlo, dd,
                rpsi[r], rphi[r], rwr[r], whi, wlo, rb[r], Tp, input);
    }

    k_bnlin<128,64,false><<<512, 128, 0, stream>>>(A, wpf+O_D1, d1_b, dbn_g, dbn_b, Cdec, input);
    k_dec2<<<512, 256, 0, stream>>>(Cdec, wpf+O_D2, d2_b, wpf+O_BC, bc_b, wpf+O_BG, bg_b, d_out, input);
}

// Round 13
// 293.834 us; speedup vs baseline: 1.1491x; 1.1491x over previous
//
#include <hip/hip_runtime.h>
#include <hip/hip_bf16.h>

// ---------------------------------------------------------------------------
// Generator_58737972740271.  R13 = R11 revert (R12's 32-row tiles regressed:
// per-block fixed costs + 2x Tp outweighed occupancy) + three targeted fixes:
// (1) encoder bnlin1+bnlin2 fused (same per-n ownership; C stays in LDS),
// (2) relfuse stages UT tile into LDS coalesced (was 2048 scattered 8-B
//     global loads/block), (3) u/xt staging stride 64 -> 72 to break the
//     16-way bank conflict in the T-partial ds_read_b128 pattern.
// ---------------------------------------------------------------------------

typedef __hip_bfloat16 bf16;
typedef unsigned short ushort_t;
typedef float v4f __attribute__((ext_vector_type(4)));
typedef short v8s __attribute__((ext_vector_type(8)));
#define MFMA_BF16 __builtin_amdgcn_mfma_f32_16x16x32_bf16

#define NB 32
#define NN 1024
#define XSTRIDE 72   // padded [n][r] stride (16B-aligned, breaks bank conflicts)

__device__ __forceinline__ float ldin(const void* p, size_t i, int f32){
    return f32 ? ((const float*)p)[i] : __bfloat162float(((const bf16*)p)[i]);
}
__device__ __forceinline__ float bf2f(ushort_t u){
    return __uint_as_float((unsigned)u << 16);
}
__device__ __forceinline__ ushort_t f2bf(float v){
    bf16 h = __float2bfloat16(v);
    ushort_t s; __builtin_memcpy(&s, &h, 2);
    return s;
}
__device__ __forceinline__ void unpack8(uint4 v, float* f){
    f[0] = __uint_as_float(v.x << 16);
    f[1] = __uint_as_float(v.x & 0xffff0000u);
    f[2] = __uint_as_float(v.y << 16);
    f[3] = __uint_as_float(v.y & 0xffff0000u);
    f[4] = __uint_as_float(v.z << 16);
    f[5] = __uint_as_float(v.z & 0xffff0000u);
    f[6] = __uint_as_float(v.w << 16);
    f[7] = __uint_as_float(v.w & 0xffff0000u);
}

__device__ __forceinline__ int detect_dev(const void* inp){
    __shared__ int sflag;
    int t = threadIdx.x;
    if (t < 64){
        unsigned v = ((const unsigned*)inp)[t];
        unsigned long long m = __ballot((v & 0x80008000u) != 0u);
        if (t == 0) sflag = (__popcll(m) > 4) ? 1 : 0;
    }
    __syncthreads();
    return sflag;
}

// ---------------- prep: weights --------------------------------------------
struct PrepArgs {
    const void* w[11];
    int K[11], O[11], off[11];
};

__global__ __launch_bounds__(256) void k_prep(PrepArgs a, float* __restrict__ wpf,
                                              ushort_t* __restrict__ whi, ushort_t* __restrict__ wlo,
                                              const void* __restrict__ detin){
    int f32 = detect_dev(detin);
    int s = blockIdx.y;
    int idx = blockIdx.x*256 + threadIdx.x;
    if (s < 6){
        int K = a.K[s], O = a.O[s];
        if (idx >= K*O) return;
        int k = idx / O, j = idx - k*O;
        wpf[a.off[s] + idx] = ldin(a.w[s], (size_t)j*K + k, f32);
    } else {
        if (idx >= 16384) return;
        int n = idx >> 7, k = idx & 127;
        float v = ldin(a.w[s], (size_t)n*128 + k, f32);
        ushort_t h = f2bf(v);
        ushort_t l = f2bf(v - bf2f(h));
        int di = (s - 6)*16384 + ((k >> 3)*128 + n)*8 + (k & 7);
        whi[di] = h; wlo[di] = l;
    }
}

// ---------------- fused encoder: lin+BN+ReLU (32->64) then (64->128) -------
// block = 128 threads = 2 waves; wave w handles n = blk*2 + w through BOTH
// layers (BatchNorm channel dim is n -> identical ownership; C stays in LDS).
__global__ __launch_bounds__(128) void k_bnlin12(
    const void* __restrict__ xin,
    const float* __restrict__ Wt1, const void* __restrict__ b1v,
    const void* __restrict__ g1, const void* __restrict__ bb1,
    const float* __restrict__ Wt2, const void* __restrict__ b2v,
    const void* __restrict__ g2, const void* __restrict__ bb2,
    ushort_t* __restrict__ out, const void* __restrict__ detin)
{
    int f32 = detect_dev(detin);
    __shared__ __align__(16) float wt1[32*64];      // 8 KB
    __shared__ __align__(16) float wt2[64*128];     // 32 KB
    __shared__ __align__(16) float xst[2][32*36];   // 9.2 KB
    __shared__ __align__(16) float cst[2][64*36];   // 18.4 KB
    int t = threadIdx.x;
    int w = t >> 6, lane = t & 63;
    int n = blockIdx.x*2 + w;

    for (int i = t; i < 32*64/4; i += 128)
        ((float4*)wt1)[i] = ((const float4*)Wt1)[i];
    for (int i = t; i < 64*128/4; i += 128)
        ((float4*)wt2)[i] = ((const float4*)Wt2)[i];
    for (int i = lane; i < 32*4; i += 64){
        int b = i >> 2, g = i & 3;
        float f[8];
        if (f32){
            const float* src = (const float*)xin + ((size_t)b*NN + n)*32 + g*8;
            float4 v0 = ((const float4*)src)[0];
            float4 v1 = ((const float4*)src)[1];
            f[0]=v0.x; f[1]=v0.y; f[2]=v0.z; f[3]=v0.w;
            f[4]=v1.x; f[5]=v1.y; f[6]=v1.z; f[7]=v1.w;
        } else {
            uint4 v = *(const uint4*)((const ushort_t*)xin + ((size_t)b*NN + n)*32 + (size_t)g*8);
            unpack8(v, f);
        }
        #pragma unroll
        for (int j=0;j<8;j++) xst[w][(g*8+j)*36 + b] = f[j];
    }
    __syncthreads();

    // ---- layer 1: K=32, O=64.  lane -> b0=(lane%8)*4, j0=(lane/8)*8 ----
    {
        int b0 = (lane & 7)*4, j0 = (lane >> 3)*8;
        float acc[4][8];
        #pragma unroll
        for (int i=0;i<4;i++)
            #pragma unroll
            for (int j=0;j<8;j++) acc[i][j] = 0.f;
        for (int k = 0; k < 32; k++){
            float xv[4], wv[8];
            *(float4*)&xv[0] = *(const float4*)&xst[w][k*36 + b0];
            *(float4*)&wv[0] = *(const float4*)&wt1[k*64 + j0];
            *(float4*)&wv[4] = *(const float4*)&wt1[k*64 + j0 + 4];
            #pragma unroll
            for (int i=0;i<4;i++)
                #pragma unroll
                for (int j=0;j<8;j++) acc[i][j] = fmaf(xv[i], wv[j], acc[i][j]);
        }
        float bj[8];
        #pragma unroll
        for (int j=0;j<8;j++) bj[j] = ldin(b1v, j0+j, f32);
        float s1 = 0.f, s2 = 0.f;
        #pragma unroll
        for (int i=0;i<4;i++)
            #pragma unroll
            for (int j=0;j<8;j++){
                float a = acc[i][j] + bj[j];
                acc[i][j] = a; s1 += a; s2 = fmaf(a, a, s2);
            }
        #pragma unroll
        for (int off = 32; off > 0; off >>= 1){
            s1 += __shfl_down(s1, off);
            s2 += __shfl_down(s2, off);
        }
        s1 = __shfl(s1, 0); s2 = __shfl(s2, 0);
        float m  = s1 / 2048.f;
        float vv = s2 / 2048.f - m*m;
        float rs = rsqrtf(vv + 1e-5f);
        float gv = ldin(g1, n, f32), bv = ldin(bb1, n, f32);
        #pragma unroll
        for (int i=0;i<4;i++)
            #pragma unroll
            for (int j=0;j<8;j++)
                cst[w][(j0+j)*36 + b0+i] =
                    fmaxf(fmaf(gv*(acc[i][j]-m), rs, bv), 0.f);
    }
    __syncthreads();

    // ---- layer 2: K=64, O=128.  lane -> b0=(lane%4)*8, j0=(lane/4)*8 ----
    {
        int b0 = (lane & 3)*8, j0 = (lane >> 2)*8;
        float acc[8][8];
        #pragma unroll
        for (int i=0;i<8;i++)
            #pragma unroll
            for (int j=0;j<8;j++) acc[i][j] = 0.f;
        for (int k = 0; k < 64; k++){
            float xv[8], wv[8];
            *(float4*)&xv[0] = *(const float4*)&cst[w][k*36 + b0];
            *(float4*)&xv[4] = *(const float4*)&cst[w][k*36 + b0 + 4];
            *(float4*)&wv[0] = *(const float4*)&wt2[k*128 + j0];
            *(float4*)&wv[4] = *(const float4*)&wt2[k*128 + j0 + 4];
            #pragma unroll
            for (int i=0;i<8;i++)
                #pragma unroll
                for (int j=0;j<8;j++) acc[i][j] = fmaf(xv[i], wv[j], acc[i][j]);
        }
        float bj[8];
        #pragma unroll
        for (int j=0;j<8;j++) bj[j] = ldin(b2v, j0+j, f32);
        float s1 = 0.f, s2 = 0.f;
        #pragma unroll
        for (int i=0;i<8;i++)
            #pragma unroll
            for (int j=0;j<8;j++){
                float a = acc[i][j] + bj[j];
                acc[i][j] = a; s1 += a; s2 = fmaf(a, a, s2);
            }
        #pragma unroll
        for (int off = 32; off > 0; off >>= 1){
            s1 += __shfl_down(s1, off);
            s2 += __shfl_down(s2, off);
        }
        s1 = __shfl(s1, 0); s2 = __shfl(s2, 0);
        float m  = s1 / 4096.f;
        float vv = s2 / 4096.f - m*m;
        float rs = rsqrtf(vv + 1e-5f);
        float gv = ldin(g2, n, f32), bv = ldin(bb2, n, f32);
        #pragma unroll
        for (int i=0;i<8;i++){
            union { uint4 u; ushort_t s[8]; } pk;
            #pragma unroll
            for (int j=0;j<8;j++)
                pk.s[j] = f2bf(fmaxf(fmaf(gv*(acc[i][j]-m), rs, bv), 0.f));
            *(uint4*)(out + ((size_t)(b0+i)*NN + n)*128 + j0) = pk.u;
        }
    }
}

// ---------------- fused linear + BatchNorm(channel=n) + ReLU (decoder) -----
template<int K, int O>
__global__ __launch_bounds__(128) void k_bnlin(
    const ushort_t* __restrict__ xin, const float* __restrict__ Wt,
    const void* __restrict__ bias, const void* __restrict__ bng,
    const void* __restrict__ bnb, ushort_t* __restrict__ out,
    const void* __restrict__ detin)
{
    int f32 = detect_dev(detin);
    constexpr int BR  = O/16;
    constexpr int NBT = 32/BR;
    constexpr int G   = K/8;
    __shared__ __align__(16) float wt[K*O];
    __shared__ __align__(16) float xst[2][K*36];
    int t = threadIdx.x;
    int w = t >> 6, lane = t & 63;
    int n = blockIdx.x*2 + w;

    for (int i = t; i < K*O/4; i += 128)
        ((float4*)wt)[i] = ((const float4*)Wt)[i];
    for (int i = lane; i < 32*G; i += 64){
        int b = i / G, g = i - b*G;
        float f[8];
        uint4 v = *(const uint4*)(xin + ((size_t)b*NN + n)*K + (size_t)g*8);
        unpack8(v, f);
        #pragma unroll
        for (int j=0;j<8;j++) xst[w][(g*8+j)*36 + b] = f[j];
    }
    __syncthreads();

    int bt = lane % NBT, jt = lane / NBT;
    int b0 = bt*BR, j0 = jt*8;
    const float* xw = xst[w];
    float acc[BR][8];
    #pragma unroll
    for (int i=0;i<BR;i++)
        #pragma unroll
        for (int j=0;j<8;j++) acc[i][j] = 0.f;

    for (int k = 0; k < K; k++){
        float xv[BR], wv[8];
        #pragma unroll
        for (int i=0;i<BR;i+=4)
            *(float4*)&xv[i] = *(const float4*)&xw[k*36 + b0 + i];
        *(float4*)&wv[0] = *(const float4*)&wt[k*O + j0];
        *(float4*)&wv[4] = *(const float4*)&wt[k*O + j0 + 4];
        #pragma unroll
        for (int i=0;i<BR;i++)
            #pragma unroll
            for (int j=0;j<8;j++) acc[i][j] = fmaf(xv[i], wv[j], acc[i][j]);
    }

    float bj[8];
    #pragma unroll
    for (int j=0;j<8;j++) bj[j] = ldin(bias, j0+j, f32);
    float s1 = 0.f, s2 = 0.f;
    #pragma unroll
    for (int i=0;i<BR;i++)
        #pragma unroll
        for (int j=0;j<8;j++){
            float a = acc[i][j] + bj[j];
            acc[i][j] = a; s1 += a; s2 = fmaf(a, a, s2);
        }
    #pragma unroll
    for (int off = 32; off > 0; off >>= 1){
        s1 += __shfl_down(s1, off);
        s2 += __shfl_down(s2, off);
    }
    s1 = __shfl(s1, 0); s2 = __shfl(s2, 0);
    const float M = 32.f * O;
    float m  = s1 / M;
    float vv = s2 / M - m*m;
    float rs = rsqrtf(vv + 1e-5f);
    float gv = ldin(bng, n, f32), bv = ldin(bnb, n, f32);
    #pragma unroll
    for (int i=0;i<BR;i++){
        union { uint4 u; ushort_t s[8]; } pk;
        #pragma unroll
        for (int j=0;j<8;j++)
            pk.s[j] = f2bf(fmaxf(fmaf(gv*(acc[i][j]-m), rs, bv), 0.f));
        *(uint4*)(out + ((size_t)(b0+i)*NN + n)*O + j0) = pk.u;
    }
}

// ---------------- shared tails for the fused MFMA kernels (64-row) ---------
// Block owns rows [row0, row0+64).  Lane owns values at (r = m*16+quad*4+reg,
// n = w*32+nt*16+col).  xs: A-layout buffer (reused for u [n][XSTRIDE]),
// xt: [c][XSTRIDE] transpose of x' (also used to stage UT in relfuse).

__device__ __forceinline__ void tail_stage_x(ushort_t* xs, ushort_t* xt,
                                             const float o[2][16],
                                             int w, int col, int quad){
    #pragma unroll
    for (int nt=0;nt<2;nt++){
        int n = w*32 + nt*16 + col;
        #pragma unroll
        for (int m=0;m<4;m++){
            union { uint2 u2; ushort_t s[4]; } pk;
            #pragma unroll
            for (int reg=0;reg<4;reg++){
                int r = m*16 + quad*4 + reg;
                ushort_t hv = f2bf(o[nt][m*4+reg]);
                xs[((n>>3)*64 + r)*8 + (n&7)] = hv;
                pk.s[reg] = hv;
            }
            *(uint2*)&xt[n*XSTRIDE + m*16 + quad*4] = pk.u2;
        }
    }
}

__device__ __forceinline__ void tail_write_A(const ushort_t* xs, ushort_t* A,
                                             size_t row0, int t){
    uint4* dst = (uint4*)(A + row0*128);
    #pragma unroll
    for (int c = 0; c < 4; c++){
        int i = t + c*256;
        int r = i >> 4, kg = i & 15;
        dst[i] = *(const uint4*)&xs[(kg*64 + r)*8];
    }
}

// next linear: U = relu(x'·W^T + b) -> UT; dvec; then the block's 64-row
// T-partial  Tp[s][b][c][n] (bf16) = sum_r u[r][n] * x'[r][c]  via MFMA.
__device__ __forceinline__ void tail_lin_relu_T(ushort_t* xs, ushort_t* xt,
    ushort_t* UT, const ushort_t* Whi, const ushort_t* Wlo, const void* bias,
    float* dvec, ushort_t* Tp,
    size_t row0, int b, int rbase, int t, int w, int col, int quad, int f32)
{
    if (t < 64){
        float s = 0.f;
        #pragma unroll 8
        for (int k=0;k<128;k++){
            float v = bf2f(xs[((k>>3)*64 + t)*8 + (k&7)]);
            s = fmaf(v, v, s);
        }
        dvec[row0 + t] = s;
    }
    v4f acc[4][2];
    #pragma unroll
    for (int m=0;m<4;m++)
        #pragma unroll
        for (int nt=0;nt<2;nt++) acc[m][nt] = (v4f){0.f,0.f,0.f,0.f};
    #pragma unroll
    for (int kt = 0; kt < 4; kt++){
        int kg = kt*4 + quad;
        v8s a[4], bh[2], bl[2];
        #pragma unroll
        for (int nt=0;nt<2;nt++){
            int n = w*32 + nt*16 + col;
            bh[nt] = *(const v8s*)&Whi[(kg*128 + n)*8];
            bl[nt] = *(const v8s*)&Wlo[(kg*128 + n)*8];
        }
        #pragma unroll
        for (int m=0;m<4;m++)
            a[m] = *(const v8s*)&xs[(kg*64 + m*16 + col)*8];
        #pragma unroll
        for (int m=0;m<4;m++)
            #pragma unroll
            for (int nt=0;nt<2;nt++){
                acc[m][nt] = MFMA_BF16(a[m], bh[nt], acc[m][nt], 0, 0, 0);
                acc[m][nt] = MFMA_BF16(a[m], bl[nt], acc[m][nt], 0, 0, 0);
            }
    }
    float u[2][16];
    #pragma unroll
    for (int nt=0;nt<2;nt++){
        int n = w*32 + nt*16 + col;
        float bn = ldin(bias, n, f32);
        #pragma unroll
        for (int m=0;m<4;m++)
            #pragma unroll
            for (int reg=0;reg<4;reg++)
                u[nt][m*4+reg] = fmaxf(acc[m][nt][reg] + bn, 0.f);
    }
    __syncthreads();           // xs reads (a-frags, dvec) done
    #pragma unroll
    for (int nt=0;nt<2;nt++){
        int n = w*32 + nt*16 + col;
        #pragma unroll
        for (int m=0;m<4;m++){
            union { uint2 u2; ushort_t s[4]; } pk;
            #pragma unroll
            for (int reg=0;reg<4;reg++)
                pk.s[reg] = f2bf(u[nt][m*4+reg]);
            *(uint2*)&xs[n*XSTRIDE + m*16 + quad*4] = pk.u2;  // u in [n][72r]
        }
    }
    __syncthreads();
    #pragma unroll
    for (int c = 0; c < 4; c++){
        int i = t + c*256;
        int n = i >> 3, sg = i & 7;
        *(uint4*)&UT[((size_t)b*128 + n)*1024 + rbase + sg*8] =
            *(const uint4*)&xs[n*XSTRIDE + sg*8];
    }
    // ---- T-partial over own 64 rows: A = u [n][72r], B = x' [c][72r] ----
    v4f tacc[4][4];
    #pragma unroll
    for (int m=0;m<4;m++)
        #pragma unroll
        for (int q=0;q<4;q++) tacc[m][q] = (v4f){0.f,0.f,0.f,0.f};
    int wn = (w & 1)*64, wc = (w >> 1)*64;
    #pragma unroll
    for (int kt = 0; kt < 2; kt++){
        int kg = kt*4 + quad;
        v8s a[4], bb[4];
        #pragma unroll
        for (int m=0;m<4;m++)
            a[m] = *(const v8s*)&xs[(wn + m*16 + col)*XSTRIDE + kg*8];
        #pragma unroll
        for (int q=0;q<4;q++)
            bb[q] = *(const v8s*)&xt[(wc + q*16 + col)*XSTRIDE + kg*8];
        #pragma unroll
        for (int m=0;m<4;m++)
            #pragma unroll
            for (int q=0;q<4;q++)
                tacc[m][q] = MFMA_BF16(a[m], bb[q], tacc[m][q], 0, 0, 0);
    }
    int s16 = (int)((row0 >> 6) & 15);
    ushort_t* dst = Tp + ((size_t)(s16*NB + b) << 14);   // [c][n] bf16
    #pragma unroll
    for (int m=0;m<4;m++)
        #pragma unroll
        for (int q=0;q<4;q++){
            int c = wc + q*16 + col;
            union { uint2 u2; ushort_t s[4]; } pk;
            #pragma unroll
            for (int reg=0;reg<4;reg++)
                pk.s[reg] = f2bf(tacc[m][q][reg]);       // n-consecutive
            *(uint2*)&dst[c*128 + wn + m*16 + quad*4] = pk.u2;
        }
}

// ---------------- fused: enc3 sigmoid + relation-1 U + T-partial -----------
__global__ __launch_bounds__(256) void k_linfuse0(
    const ushort_t* __restrict__ xin,                 // E2, row-major
    const ushort_t* __restrict__ W3h, const ushort_t* __restrict__ W3l,
    const void* __restrict__ b3,
    const ushort_t* __restrict__ W1h, const ushort_t* __restrict__ W1l,
    const void* __restrict__ b1,
    ushort_t* __restrict__ A, ushort_t* __restrict__ UT,
    float* __restrict__ dvec, ushort_t* __restrict__ Tp,
    const void* __restrict__ detin)
{
    __shared__ __align__(16) ushort_t xs[128*XSTRIDE];
    __shared__ __align__(16) ushort_t xt[128*XSTRIDE];
    int f32 = detect_dev(detin);
    int t = threadIdx.x;
    size_t row0 = (size_t)blockIdx.x * 64;
    int b = (int)(row0 >> 10), rbase = (int)(row0 & 1023);
    {
        const uint4* src = (const uint4*)(xin + row0*128);
        #pragma unroll
        for (int c = 0; c < 4; c++){
            int i = t + c*256;
            int r = i >> 4, kg = i & 15;
            *(uint4*)&xs[(kg*64 + r)*8] = src[i];
        }
    }
    __syncthreads();
    int w = t >> 6, lane = t & 63;
    int col = lane & 15, quad = lane >> 4;
    v4f acc[4][2];
    #pragma unroll
    for (int m=0;m<4;m++)
        #pragma unroll
        for (int nt=0;nt<2;nt++) acc[m][nt] = (v4f){0.f,0.f,0.f,0.f};
    #pragma unroll
    for (int kt = 0; kt < 4; kt++){
        int kg = kt*4 + quad;
        v8s a[4], bh[2], bl[2];
        #pragma unroll
        for (int nt=0;nt<2;nt++){
            int n = w*32 + nt*16 + col;
            bh[nt] = *(const v8s*)&W3h[(kg*128 + n)*8];
            bl[nt] = *(const v8s*)&W3l[(kg*128 + n)*8];
        }
        #pragma unroll
        for (int m=0;m<4;m++)
            a[m] = *(const v8s*)&xs[(kg*64 + m*16 + col)*8];
        #pragma unroll
        for (int m=0;m<4;m++)
            #pragma unroll
            for (int nt=0;nt<2;nt++){
                acc[m][nt] = MFMA_BF16(a[m], bh[nt], acc[m][nt], 0, 0, 0);
                acc[m][nt] = MFMA_BF16(a[m], bl[nt], acc[m][nt], 0, 0, 0);
            }
    }
    float o[2][16];
    #pragma unroll
    for (int nt=0;nt<2;nt++){
        int n = w*32 + nt*16 + col;
        float bn = ldin(b3, n, f32);
        #pragma unroll
        for (int m=0;m<4;m++)
            #pragma unroll
            for (int reg=0;reg<4;reg++){
                float v = acc[m][nt][reg] + bn;
                o[nt][m*4+reg] = 1.f/(1.f+expf(-v));
            }
    }
    __syncthreads();
    tail_stage_x(xs, xt, o, w, col, quad);
    __syncthreads();
    tail_write_A(xs, A, row0, t);
    tail_lin_relu_T(xs, xt, UT, W1h, W1l, b1, dvec, Tp,
                    row0, b, rbase, t, w, col, quad, f32);
}

// ---------------- reduce 16 bf16 partials -> Tt hi/lo (MFMA-B layout) ------
__global__ __launch_bounds__(256) void k_tredb(const ushort_t* __restrict__ Tp,
                                               ushort_t* __restrict__ Thi, ushort_t* __restrict__ Tlo){
    int tau = blockIdx.x*256 + threadIdx.x;     // 65536 total
    int b = tau >> 11;
    int j2 = tau & 2047;
    int cg = j2 >> 7, n = j2 & 127;
    float sum[8] = {0,0,0,0,0,0,0,0};
    #pragma unroll
    for (int s = 0; s < 16; s++){
        const ushort_t* src = Tp + ((size_t)(s*NB + b) << 14) + cg*8*128 + n;
        #pragma unroll
        for (int cc = 0; cc < 8; cc++)
            sum[cc] += bf2f(src[cc*128]);
    }
    union { uint4 u; ushort_t s[8]; } ph, pl;
    #pragma unroll
    for (int cc = 0; cc < 8; cc++){
        ushort_t h = f2bf(sum[cc]);
        ph.s[cc] = h;
        pl.s[cc] = f2bf(sum[cc] - bf2f(h));
    }
    size_t di = ((size_t)b << 14) + ((size_t)cg*128 + n)*8;
    *(uint4*)&Thi[di] = ph.u;
    *(uint4*)&Tlo[di] = pl.u;
}

// ---------------- fused: relout_r (+ lin_{r+1} + T-partial unless LAST) ----
template<int LAST>
__global__ __launch_bounds__(256) void k_relfuse(
    ushort_t* __restrict__ x, ushort_t* __restrict__ UT,
    const ushort_t* __restrict__ Thi, const ushort_t* __restrict__ Tlo,
    float* __restrict__ dvec,
    const void* __restrict__ psi, const void* __restrict__ phi, const void* __restrict__ wr,
    const ushort_t* __restrict__ Wnh, const ushort_t* __restrict__ Wnl,
    const void* __restrict__ bnext, ushort_t* __restrict__ Tp,
    const void* __restrict__ detin)
{
    __shared__ __align__(16) ushort_t xs[128*XSTRIDE];
    __shared__ __align__(16) ushort_t xt[128*XSTRIDE];
    int f32 = detect_dev(detin);
    int t = threadIdx.x;
    size_t row0 = (size_t)blockIdx.x * 64;
    int b = (int)(row0 >> 10), rbase = (int)(row0 & 1023);
    {
        const uint4* src = (const uint4*)(x + row0*128);
        const ushort_t* utb = UT + (size_t)b*128*1024 + rbase;
        #pragma unroll
        for (int c = 0; c < 4; c++){
            int i = t + c*256;
            int r = i >> 4, kg = i & 15;
            *(uint4*)&xs[(kg*64 + r)*8] = src[i];
            int n2 = i >> 3, sg = i & 7;          // stage UT tile -> xt [n][72]
            *(uint4*)&xt[n2*XSTRIDE + sg*8] =
                *(const uint4*)&utb[(size_t)n2*1024 + sg*8];
        }
    }
    __syncthreads();
    float alpha = ldin(wr,0,f32) * ldin(psi,0,f32) * ldin(phi,0,f32) * (1.f/1024.f);
    int w = t >> 6, lane = t & 63;
    int col = lane & 15, quad = lane >> 4;
    const ushort_t* sh = Thi + ((size_t)b << 14);
    const ushort_t* sl = Tlo + ((size_t)b << 14);
    v4f acc[4][2];
    #pragma unroll
    for (int m=0;m<4;m++)
        #pragma unroll
        for (int nt=0;nt<2;nt++) acc[m][nt] = (v4f){0.f,0.f,0.f,0.f};
    #pragma unroll
    for (int kt = 0; kt < 4; kt++){
        int kg = kt*4 + quad;
        v8s a[4], bh[2], bl[2];
        #pragma unroll
        for (int nt=0;nt<2;nt++){
            int n = w*32 + nt*16 + col;
            bh[nt] = *(const v8s*)&sh[(kg*128 + n)*8];
            bl[nt] = *(const v8s*)&sl[(kg*128 + n)*8];
        }
        #pragma unroll
        for (int m=0;m<4;m++)
            a[m] = *(const v8s*)&xs[(kg*64 + m*16 + col)*8];
        #pragma unroll
        for (int m=0;m<4;m++)
            #pragma unroll
            for (int nt=0;nt<2;nt++){
                acc[m][nt] = MFMA_BF16(a[m], bh[nt], acc[m][nt], 0, 0, 0);
                acc[m][nt] = MFMA_BF16(a[m], bl[nt], acc[m][nt], 0, 0, 0);
            }
    }
    float o[2][16];
    #pragma unroll
    for (int m=0;m<4;m++){
        float4 d4 = *(const float4*)&dvec[row0 + m*16 + quad*4];
        const float* dr = (const float*)&d4;
        #pragma unroll
        for (int nt=0;nt<2;nt++){
            int n = w*32 + nt*16 + col;
            #pragma unroll
            for (int reg=0;reg<4;reg++){
                int r = m*16 + quad*4 + reg;
                float ufv = bf2f(xt[n*XSTRIDE + r]);     // U from LDS (staged)
                float xv = bf2f(xs[((n>>3)*64 + r)*8 + (n&7)]);
                o[nt][m*4+reg] = fmaf(alpha, acc[m][nt][reg] - dr[reg]*ufv, xv);
            }
        }
    }
    __syncthreads();           // all xs / xt / dvec reads done
    tail_stage_x(xs, xt, o, w, col, quad);
    __syncthreads();
    tail_write_A(xs, x, row0, t);
    if (!LAST)
        tail_lin_relu_T(xs, xt, UT, Wnh, Wnl, bnext, dvec, Tp,
                        row0, b, rbase, t, w, col, quad, f32);
}

// ---------------- decoder tail (512 blocks x 8-tile loop) ------------------
__global__ __launch_bounds__(256) void k_dec2(
    const ushort_t* __restrict__ x,       // [B,N,64]
    const float* __restrict__ W2t, const void* __restrict__ b2,
    const float* __restrict__ Wct, const void* __restrict__ bcb,
    const float* __restrict__ Wgt, const void* __restrict__ bgb,
    void* __restrict__ out, const void* __restrict__ detin)
{
    int f32 = detect_dev(detin);
    __shared__ __align__(16) float w2[64*32];
    __shared__ __align__(16) float wc[32*28];
    __shared__ __align__(16) float wg[32*4];
    __shared__ __align__(16) float xsd[8][64];
    __shared__ float hs[8][33];
    int t = threadIdx.x;
    for (int i=t;i<512;i+=256)  ((float4*)w2)[i] = ((const float4*)W2t)[i];
    if (t < 224) ((float4*)wc)[t] = ((const float4*)Wct)[t];
    if (t < 32)  ((float4*)wg)[t] = ((const float4*)Wgt)[t];
    int j = t & 31, r = t >> 5;
    for (int tile = blockIdx.x; tile < 4096; tile += 512){
        size_t row0 = (size_t)tile * 8;
        __syncthreads();
        if (t < 64){
            int row = t >> 3, seg = t & 7;
            uint4 v = *(const uint4*)&x[(row0 + row)*64 + seg*8];
            float f[8]; unpack8(v, f);
            *(float4*)&xsd[row][seg*8]   = make_float4(f[0],f[1],f[2],f[3]);
            *(float4*)&xsd[row][seg*8+4] = make_float4(f[4],f[5],f[6],f[7]);
        }
        __syncthreads();
        float a = ldin(b2, j, f32);
        #pragma unroll 8
        for (int k=0;k<64;k++) a = fmaf(xsd[r][k], w2[k*32 + j], a);
        hs[r][j] = fmaxf(a, 0.f);
        __syncthreads();
        float o;
        if (j < 28){
            o = ldin(bcb, j, f32);
            #pragma unroll
            for (int k=0;k<32;k++) o = fmaf(hs[r][k], wc[k*28 + j], o);
        } else {
            int jj = j - 28;
            o = ldin(bgb, jj, f32);
            #pragma unroll
            for (int k=0;k<32;k++) o = fmaf(hs[r][k], wg[k*4 + jj], o);
        }
        size_t oi = (row0 + r)*32 + j;
        if (f32) ((float*)out)[oi] = o;
        else     ((ushort_t*)out)[oi] = f2bf(o);
    }
}

// ---------------------------------------------------------------------------
enum { O_E1=0, O_E2=2048, O_D1=10240, O_D2=18432, O_BC=20480, O_BG=21376 };

extern "C" void kernel_launch(void* const* d_in, const int* in_sizes, int n_in,
                              void* d_out, int out_size, void* d_ws, size_t ws_size,
                              hipStream_t stream)
{
    (void)in_sizes; (void)n_in; (void)out_size; (void)ws_size;
    const void* input = d_in[0];
    const void* e1_W = d_in[1];  const void* e1_b = d_in[2];
    const void* bn1_g = d_in[3]; const void* bn1_b = d_in[4];
    const void* e2_W = d_in[5];  const void* e2_b = d_in[6];
    const void* bn2_g = d_in[7]; const void* bn2_b = d_in[8];
    const void* e3_W = d_in[9];  const void* e3_b = d_in[10];
    const void *rW[4], *rb[4], *rpsi[4], *rphi[4], *rwr[4];
    for (int r = 0; r < 4; r++){
        rW[r]   = d_in[11 + r*5 + 0];
        rb[r]   = d_in[11 + r*5 + 1];
        rpsi[r] = d_in[11 + r*5 + 2];
        rphi[r] = d_in[11 + r*5 + 3];
        rwr[r]  = d_in[11 + r*5 + 4];
    }
    const void* d1_W = d_in[31]; const void* d1_b = d_in[32];
    const void* dbn_g = d_in[33];const void* dbn_b = d_in[34];
    const void* d2_W = d_in[35]; const void* d2_b = d_in[36];
    const void* bc_W = d_in[37]; const void* bc_b = d_in[38];
    const void* bg_W = d_in[39]; const void* bg_b = d_in[40];

    // ---- workspace layout (44.6 MB), float offsets (all 16B-aligned) ----
    float*    ws_f = (float*)d_ws;
    float*    wpf  = ws_f;                          // 21504 f
    float*    dd   = ws_f + 21504;                  // 32768 f
    ushort_t* whi  = (ushort_t*)(ws_f + 54272);     // 5*16384 us
    ushort_t* wlo  = (ushort_t*)(ws_f + 95232);     // 5*16384 us
    ushort_t* Thi  = (ushort_t*)(ws_f + 136192);    // 524288 us
    ushort_t* Tlo  = (ushort_t*)(ws_f + 398336);    // 524288 us
    ushort_t* Tp   = (ushort_t*)(ws_f + 660480);    // 16*32*16384 us (bf16)
    ushort_t* A    = (ushort_t*)(ws_f + 4854784);   // [32768][128] bf16
    ushort_t* UT   = (ushort_t*)(ws_f + 6951936);   // [32][128][1024] bf16
    ushort_t* E2   = (ushort_t*)(ws_f + 9049088);   // [32768][128] bf16
    ushort_t* Cdec = UT;                            // [32768][64] overlays UT

    PrepArgs pa;
    const void* srcs[11] = {e1_W, e2_W, d1_W, d2_W, bc_W, bg_W,
                            e3_W, rW[0], rW[1], rW[2], rW[3]};
    const int  Ks[11]   = {32,64,128,64,32,32, 128,128,128,128,128};
    const int  Os[11]   = {64,128,64,32,28,4,  128,128,128,128,128};
    const int  offs[11] = {O_E1,O_E2,O_D1,O_D2,O_BC,O_BG, 0,0,0,0,0};
    for (int i=0;i<11;i++){ pa.w[i]=srcs[i]; pa.K[i]=Ks[i]; pa.O[i]=Os[i]; pa.off[i]=offs[i]; }

    k_prep<<<dim3(64,11), 256, 0, stream>>>(pa, wpf, whi, wlo, input);
    k_bnlin12<<<512, 128, 0, stream>>>(input,
                                       wpf+O_E1, e1_b, bn1_g, bn1_b,
                                       wpf+O_E2, e2_b, bn2_g, bn2_b,
                                       E2, input);
    k_linfuse0<<<512, 256, 0, stream>>>(E2, whi, wlo, e3_b,
                                        whi + 16384, wlo + 16384, rb[0],
                                        A, UT, dd, Tp, input);

    for (int r = 0; r < 4; r++){
        k_tredb<<<256, 256, 0, stream>>>(Tp, Thi, Tlo);
        if (r < 3)
            k_relfuse<0><<<512, 256, 0, stream>>>(A, UT, Thi, Tlo, dd,
                rpsi[r], rphi[r], rwr[r],
                whi + (size_t)(2+r)*16384, wlo + (size_t)(2+r)*16384, rb[r+1], Tp, input);
        else
            k_relfuse<1><<<512, 256, 0, stream>>>(A, UT, Thi, Tlo, dd,
                rpsi[r], rphi[r], rwr[r], whi, wlo, rb[r], Tp, input);
    }

    k_bnlin<128,64><<<512, 128, 0, stream>>>(A, wpf+O_D1, d1_b, dbn_g, dbn_b, Cdec, input);
    k_dec2<<<512, 256, 0, stream>>>(Cdec, wpf+O_D2, d2_b, wpf+O_BC, bc_b, wpf+O_BG, bg_b, d_out, input);
}